// Round 1
// baseline (454.907 us; speedup 1.0000x reference)
//
#include <hip/hip_runtime.h>
#include <hip/hip_bf16.h>

#define B_  16
#define S_  4096
#define DIN 512
#define DH  512

typedef _Float16 f16x8 __attribute__((ext_vector_type(8)));
typedef float    f32x4 __attribute__((ext_vector_type(4)));

// ---------------- ws layout (bytes) ----------------
// W16     : [DH][DIN] fp16      @ 0        (524288)
// addv    : [B_][DH]  f32       @ 524288   (32768)   = input@W_in.T + b_in + b_ctx
// scores  : [B_][S_]  f32       @ 557056   (262144)
// wsum    : [B_][DIN] f32       @ 819200   (32768)   = sum_s attn*context
// maskflag: int                 @ 851968   (4)       1 = mask is byte-per-elem

__device__ __forceinline__ float fast_tanh(float x) {
    float e = __expf(2.f * x);
    return 1.f - 2.f * __builtin_amdgcn_rcpf(e + 1.f);
}

// ---------------- prep ----------------
__global__ void prep_kernel(const float* __restrict__ input,
                            const float* __restrict__ W_in,
                            const float* __restrict__ b_in,
                            const float* __restrict__ W_ctx,
                            const float* __restrict__ b_ctx,
                            const void*  __restrict__ mask,
                            _Float16* __restrict__ W16,
                            float* __restrict__ addv,
                            float* __restrict__ wsum,
                            int* __restrict__ maskflag) {
    int blk = blockIdx.x;
    int tid = threadIdx.x;
    if (blk < 256) {
        // W_ctx fp32 -> fp16 : 262144 elems, 4/thread
        int base = blk * 1024 + tid * 4;
        float4 wv = *(const float4*)(W_ctx + base);
        union { _Float16 f[4]; ushort4 u; } cv;
        cv.f[0] = (_Float16)wv.x; cv.f[1] = (_Float16)wv.y;
        cv.f[2] = (_Float16)wv.z; cv.f[3] = (_Float16)wv.w;
        *(ushort4*)(W16 + base) = cv.u;
    } else if (blk < 288) {
        int t = blk - 256;
        int b = t >> 1;
        int h = ((t & 1) << 8) + tid;
        __shared__ float inrow[DIN];
        inrow[tid]       = input[b * DIN + tid];
        inrow[tid + 256] = input[b * DIN + tid + 256];
        __syncthreads();
        const float* wr = W_in + (size_t)h * DIN;
        float acc = 0.f;
        for (int k = 0; k < DIN; k += 4) {
            float4 w4 = *(const float4*)(wr + k);
            acc += w4.x * inrow[k] + w4.y * inrow[k + 1]
                 + w4.z * inrow[k + 2] + w4.w * inrow[k + 3];
        }
        addv[b * DH + h] = acc + b_in[h] + b_ctx[h];
    } else if (blk == 288) {
        for (int i = tid; i < B_ * DIN; i += 256) wsum[i] = 0.f;
    } else {
        // detect mask dtype: int32 bool has nonzero bytes only at i%4==0
        const unsigned char* mb = (const unsigned char*)mask;
        int found = 0;
        for (int i = tid; i < B_ * S_; i += 256)
            if ((i & 3) != 0 && mb[i] != 0) found = 1;
        __shared__ int f;
        if (tid == 0) f = 0;
        __syncthreads();
        if (found) atomicOr(&f, 1);
        __syncthreads();
        if (tid == 0) maskflag[0] = f;
    }
}

// ---------------- score GEMM: v . tanh(addv + context@W16^T) ----------------
#define MT   64              // s-rows per block
#define NC   64              // n per chunk
#define PADH 8
#define LDA  (DIN + PADH)    // 520 halves, row stride 1040B (16B aligned)

__global__ __launch_bounds__(256, 1)
void score_kernel(const float* __restrict__ context,
                  const _Float16* __restrict__ W16,
                  const float* __restrict__ addv,
                  const float* __restrict__ v,
                  const void* __restrict__ mask,
                  const int* __restrict__ maskflag,
                  float* __restrict__ scores) {
    __shared__ _Float16 As[MT * LDA];
    __shared__ _Float16 Ws[NC * LDA];
    __shared__ float scoreAcc[MT];

    int tid = threadIdx.x;
    int b   = blockIdx.x >> 6;
    int s0  = (blockIdx.x & 63) * MT;

    if (tid < MT) scoreAcc[tid] = 0.f;

    // stage A tile: 64 rows x 512 f32 -> fp16 LDS (coalesced float4)
    const float* actx = context + ((size_t)b * S_ + s0) * DIN;
    for (int it = 0; it < 32; ++it) {
        int idx = it * 256 + tid;     // float4 index
        int row = idx >> 7;
        int c4  = idx & 127;
        float4 x = *(const float4*)(actx + row * DIN + c4 * 4);
        union { _Float16 f[4]; ushort4 u; } cv;
        cv.f[0] = (_Float16)x.x; cv.f[1] = (_Float16)x.y;
        cv.f[2] = (_Float16)x.z; cv.f[3] = (_Float16)x.w;
        *(ushort4*)&As[row * LDA + c4 * 4] = cv.u;
    }

    int wave = tid >> 6;
    int lane = tid & 63;
    int l15  = lane & 15;
    int q    = lane >> 4;
    int mt0  = (wave >> 1) * 2;  // 0 or 2
    int nt0  = (wave & 1) * 2;   // 0 or 2
    const float* avb = addv + b * DH;

    for (int ch = 0; ch < 8; ++ch) {
        __syncthreads();   // protect Ws from overwrite while previous chunk in use
        // stage W chunk: rows ch*64..+64, coalesced 16B
        const _Float16* wsrc = W16 + (size_t)(ch * NC) * DIN;
        for (int it = 0; it < 16; ++it) {
            int idx = it * 256 + tid;  // uint4 (8 halves) index
            int row = idx >> 6;
            int c8  = idx & 63;
            uint4 x = *(const uint4*)(wsrc + row * DIN + c8 * 8);
            *(uint4*)&Ws[row * LDA + c8 * 8] = x;
        }
        __syncthreads();

        f32x4 z = {0.f, 0.f, 0.f, 0.f};
        f32x4 acc[2][2] = {{z, z}, {z, z}};
        for (int k0 = 0; k0 < DIN; k0 += 32) {
            int koff = k0 + q * 8;
            f16x8 a0 = *(const f16x8*)&As[(mt0 * 16 + l15) * LDA + koff];
            f16x8 a1 = *(const f16x8*)&As[((mt0 + 1) * 16 + l15) * LDA + koff];
            f16x8 b0 = *(const f16x8*)&Ws[(nt0 * 16 + l15) * LDA + koff];
            f16x8 b1 = *(const f16x8*)&Ws[((nt0 + 1) * 16 + l15) * LDA + koff];
            acc[0][0] = __builtin_amdgcn_mfma_f32_16x16x32_f16(a0, b0, acc[0][0], 0, 0, 0);
            acc[0][1] = __builtin_amdgcn_mfma_f32_16x16x32_f16(a0, b1, acc[0][1], 0, 0, 0);
            acc[1][0] = __builtin_amdgcn_mfma_f32_16x16x32_f16(a1, b0, acc[1][0], 0, 0, 0);
            acc[1][1] = __builtin_amdgcn_mfma_f32_16x16x32_f16(a1, b1, acc[1][1], 0, 0, 0);
        }

        // epilogue: tanh + v-weighted reduce over n
        for (int mi = 0; mi < 2; ++mi) {
            float rowsum[4] = {0.f, 0.f, 0.f, 0.f};
            for (int ni = 0; ni < 2; ++ni) {
                int n = ch * NC + (nt0 + ni) * 16 + l15;
                float a_v = avb[n];
                float vv  = v[n];
                for (int r = 0; r < 4; ++r) {
                    float t = fast_tanh(acc[mi][ni][r] + a_v);
                    rowsum[r] += t * vv;
                }
            }
            for (int r = 0; r < 4; ++r) {
                float s = rowsum[r];
                s += __shfl_xor(s, 1, 16);
                s += __shfl_xor(s, 2, 16);
                s += __shfl_xor(s, 4, 16);
                s += __shfl_xor(s, 8, 16);
                if (l15 == 0) {
                    int m = (mt0 + mi) * 16 + q * 4 + r;   // C layout: row=(lane>>4)*4+reg
                    atomicAdd(&scoreAcc[m], s);
                }
            }
        }
    }
    __syncthreads();
    if (tid < MT) {
        int s = s0 + tid;
        int isByte = maskflag[0];
        int msk = isByte ? (int)((const unsigned char*)mask)[b * S_ + s]
                         : ((const int*)mask)[b * S_ + s];
        scores[b * S_ + s] = msk ? -__builtin_inff() : scoreAcc[tid];
    }
}

// ---------------- softmax ----------------
__global__ void softmax_kernel(const float* __restrict__ scores,
                               float* __restrict__ attn) {
    int b = blockIdx.x, tid = threadIdx.x;
    const float* sr = scores + b * S_;
    float mx = -__builtin_inff();
    for (int s = tid; s < S_; s += 256) mx = fmaxf(mx, sr[s]);
    for (int o = 1; o < 64; o <<= 1) mx = fmaxf(mx, __shfl_xor(mx, o, 64));
    __shared__ float rbuf[4];
    int wv = tid >> 6, ln = tid & 63;
    if (ln == 0) rbuf[wv] = mx;
    __syncthreads();
    mx = fmaxf(fmaxf(rbuf[0], rbuf[1]), fmaxf(rbuf[2], rbuf[3]));
    float sum = 0.f;
    for (int s = tid; s < S_; s += 256) sum += __expf(sr[s] - mx);
    for (int o = 1; o < 64; o <<= 1) sum += __shfl_xor(sum, o, 64);
    __syncthreads();
    if (ln == 0) rbuf[wv] = sum;
    __syncthreads();
    sum = rbuf[0] + rbuf[1] + rbuf[2] + rbuf[3];
    float inv = 1.f / sum;
    float* ab = attn + b * S_;
    for (int s = tid; s < S_; s += 256) ab[s] = __expf(sr[s] - mx) * inv;
}

// ---------------- weighted context sum (sparse skip) ----------------
__global__ __launch_bounds__(256)
void wsum_kernel(const float* __restrict__ context,
                 const float* __restrict__ attn,
                 float* __restrict__ wsum) {
    int b  = blockIdx.x >> 5;
    int s0 = (blockIdx.x & 31) * 128;
    int tid = threadIdx.x;
    float acc0 = 0.f, acc1 = 0.f;
    const float* cb = context + ((size_t)b * S_ + s0) * DIN;
    const float* ab = attn + b * S_ + s0;
    for (int s = 0; s < 128; ++s) {
        float w = ab[s];            // uniform across block -> uniform branch
        if (w > 1e-8f) {
            acc0 += w * cb[(size_t)s * DIN + tid];
            acc1 += w * cb[(size_t)s * DIN + tid + 256];
        }
    }
    atomicAdd(&wsum[b * DIN + tid], acc0);
    atomicAdd(&wsum[b * DIN + tid + 256], acc1);
}

// ---------------- hidden = W_ctx @ wsum + b_ctx ----------------
__global__ void hidden_kernel(const float* __restrict__ W_ctx,
                              const float* __restrict__ b_ctx,
                              const float* __restrict__ wsum,
                              float* __restrict__ hidden) {
    int b = blockIdx.x >> 1;
    int tid = threadIdx.x;
    int h = ((blockIdx.x & 1) << 8) + tid;
    __shared__ float wrow[DIN];
    wrow[tid]       = wsum[b * DIN + tid];
    wrow[tid + 256] = wsum[b * DIN + tid + 256];
    __syncthreads();
    const float* wr = W_ctx + (size_t)h * DIN;
    float acc = 0.f;
    for (int k = 0; k < DIN; k += 4) {
        float4 w4 = *(const float4*)(wr + k);
        acc += w4.x * wrow[k] + w4.y * wrow[k + 1]
             + w4.z * wrow[k + 2] + w4.w * wrow[k + 3];
    }
    hidden[b * DH + h] = acc + b_ctx[h];
}

extern "C" void kernel_launch(void* const* d_in, const int* in_sizes, int n_in,
                              void* d_out, int out_size, void* d_ws, size_t ws_size,
                              hipStream_t stream) {
    const float* input   = (const float*)d_in[0];
    const float* context = (const float*)d_in[1];
    const void*  mask    = d_in[2];
    const float* W_in    = (const float*)d_in[3];
    const float* b_in    = (const float*)d_in[4];
    const float* W_ctx   = (const float*)d_in[5];
    const float* b_ctx   = (const float*)d_in[6];
    const float* v       = (const float*)d_in[7];

    char* ws = (char*)d_ws;
    _Float16* W16   = (_Float16*)ws;
    float* addv     = (float*)(ws + 524288);
    float* scores   = (float*)(ws + 557056);
    float* wsum     = (float*)(ws + 819200);
    int*   maskflag = (int*)(ws + 851968);

    float* hidden = (float*)d_out;                  // [16,512]
    float* attn   = (float*)d_out + B_ * DH;        // [16,4096]

    prep_kernel<<<290, 256, 0, stream>>>(input, W_in, b_in, W_ctx, b_ctx, mask,
                                         W16, addv, wsum, maskflag);
    score_kernel<<<B_ * (S_ / MT), 256, 0, stream>>>(context, W16, addv, v,
                                                     mask, maskflag, scores);
    softmax_kernel<<<B_, 256, 0, stream>>>(scores, attn);
    wsum_kernel<<<B_ * 32, 256, 0, stream>>>(context, attn, wsum);
    hidden_kernel<<<B_ * 2, 256, 0, stream>>>(W_ctx, b_ctx, wsum, hidden);
}

// Round 2
// 431.022 us; speedup vs baseline: 1.0554x; 1.0554x over previous
//
#include <hip/hip_runtime.h>
#include <hip/hip_bf16.h>

#define B_  16
#define S_  4096
#define DIN 512
#define DH  512

typedef _Float16 f16x8 __attribute__((ext_vector_type(8)));
typedef float    f32x4 __attribute__((ext_vector_type(4)));

// ---------------- ws layout (bytes) ----------------
// W16     : [DH][DIN] fp16      @ 0        (524288)
// addv    : [B_][DH]  f32       @ 524288   (32768)   = input@W_in.T + b_in + b_ctx
// scores  : [B_][S_]  f32       @ 557056   (262144)
// wsum    : [B_][DIN] f32       @ 819200   (32768)   = sum_s attn*context
// maskflag: int                 @ 851968   (4)       1 = mask is byte-per-elem

__device__ __forceinline__ float fast_tanh(float x) {
    float e = __expf(2.f * x);
    return 1.f - 2.f * __builtin_amdgcn_rcpf(e + 1.f);
}

__device__ __forceinline__ void gload_lds16(const void* g, void* l) {
    __builtin_amdgcn_global_load_lds(
        (const __attribute__((address_space(1))) void*)g,
        (__attribute__((address_space(3))) void*)l, 16, 0, 0);
}

// ---------------- prep ----------------
__global__ void prep_kernel(const float* __restrict__ input,
                            const float* __restrict__ W_in,
                            const float* __restrict__ b_in,
                            const float* __restrict__ W_ctx,
                            const float* __restrict__ b_ctx,
                            const void*  __restrict__ mask,
                            _Float16* __restrict__ W16,
                            float* __restrict__ addv,
                            float* __restrict__ wsum,
                            int* __restrict__ maskflag) {
    int blk = blockIdx.x;
    int tid = threadIdx.x;
    if (blk < 256) {
        // W_ctx fp32 -> fp16 : 262144 elems, 4/thread
        int base = blk * 1024 + tid * 4;
        float4 wv = *(const float4*)(W_ctx + base);
        union { _Float16 f[4]; ushort4 u; } cv;
        cv.f[0] = (_Float16)wv.x; cv.f[1] = (_Float16)wv.y;
        cv.f[2] = (_Float16)wv.z; cv.f[3] = (_Float16)wv.w;
        *(ushort4*)(W16 + base) = cv.u;
    } else if (blk < 288) {
        int t = blk - 256;
        int b = t >> 1;
        int h = ((t & 1) << 8) + tid;
        __shared__ float inrow[DIN];
        inrow[tid]       = input[b * DIN + tid];
        inrow[tid + 256] = input[b * DIN + tid + 256];
        __syncthreads();
        const float* wr = W_in + (size_t)h * DIN;
        float acc = 0.f;
        for (int k = 0; k < DIN; k += 4) {
            float4 w4 = *(const float4*)(wr + k);
            acc += w4.x * inrow[k] + w4.y * inrow[k + 1]
                 + w4.z * inrow[k + 2] + w4.w * inrow[k + 3];
        }
        addv[b * DH + h] = acc + b_in[h] + b_ctx[h];
    } else if (blk == 288) {
        for (int i = tid; i < B_ * DIN; i += 256) wsum[i] = 0.f;
    } else {
        // detect mask dtype: int32 bool has nonzero bytes only at i%4==0
        const unsigned char* mb = (const unsigned char*)mask;
        int found = 0;
        for (int i = tid; i < B_ * S_; i += 256)
            if ((i & 3) != 0 && mb[i] != 0) found = 1;
        __shared__ int f;
        if (tid == 0) f = 0;
        __syncthreads();
        if (found) atomicOr(&f, 1);
        __syncthreads();
        if (tid == 0) maskflag[0] = f;
    }
}

// ---------------- score: v . tanh(addv + context@W16^T), masked ----------------
// Block: 256 thr (4 waves). Each wave: 16 s-rows, full N=512 in accumulators.
// A (context rows, fp16) in registers (64 VGPR). B staged per 32-k-half chunk
// into 32KB LDS via global_load_lds w16. Grid: 16 * 64 blocks.
#define MT 64

__global__ __launch_bounds__(256, 2)
void score_kernel(const float* __restrict__ context,
                  const _Float16* __restrict__ W16,
                  const float* __restrict__ addv,
                  const float* __restrict__ v,
                  const void* __restrict__ mask,
                  const int* __restrict__ maskflag,
                  float* __restrict__ scores) {
    // LDS B layout per k-chunk: tile j (16 n-rows) at halves [j*512 .. j*512+512):
    //   offset = j*512 + kquad*128 + (n%16)*8   (8 halves = 16B units)
    // ds_read_b128 phase banks: 4*l15 mod 32 -> 2 lanes/bank (free).
    __shared__ _Float16 Bs[32 * 512];   // 32 KiB

    const int tid  = threadIdx.x;
    const int wave = tid >> 6;
    const int lane = tid & 63;
    const int l15  = lane & 15;
    const int q    = lane >> 4;
    const int b    = blockIdx.x >> 6;
    const int s0   = (blockIdx.x & 63) * MT;

    // ---- A fragments: rows s0 + wave*16 + l15, k = kc*32 + q*8 .. +8 ----
    const float* arow = context + ((size_t)b * S_ + s0 + wave * 16 + l15) * DIN + q * 8;
    f16x8 a[16];
#pragma unroll
    for (int kc = 0; kc < 16; ++kc) {
        float4 x0 = *(const float4*)(arow + kc * 32);
        float4 x1 = *(const float4*)(arow + kc * 32 + 4);
        f16x8 t;
        t[0] = (_Float16)x0.x; t[1] = (_Float16)x0.y;
        t[2] = (_Float16)x0.z; t[3] = (_Float16)x0.w;
        t[4] = (_Float16)x1.x; t[5] = (_Float16)x1.y;
        t[6] = (_Float16)x1.z; t[7] = (_Float16)x1.w;
        a[kc] = t;
    }

    f32x4 acc[32];
#pragma unroll
    for (int j = 0; j < 32; ++j) acc[j] = (f32x4){0.f, 0.f, 0.f, 0.f};

    for (int kc = 0; kc < 16; ++kc) {
        __syncthreads();   // previous chunk's reads done before overwrite
        // stage B chunk: 512 n-rows x 64B. Wave w issues 8 x 1KB loads.
        // instr i: lane L -> global W16[(i*16 + (L&15))*512 + kc*32 + (L>>4)*8],
        //          LDS base Bs[i*512], HW places at base + L*16B.
#pragma unroll
        for (int t = 0; t < 8; ++t) {
            int i = wave * 8 + t;
            const _Float16* g = W16 + (size_t)(i * 16 + l15) * DIN + kc * 32 + q * 8;
            gload_lds16(g, &Bs[i * 512]);
        }
        __syncthreads();   // staged (barrier drains vmcnt)
#pragma unroll
        for (int j = 0; j < 32; ++j) {
            f16x8 bf = *(const f16x8*)&Bs[j * 512 + q * 128 + l15 * 8];
            acc[j] = __builtin_amdgcn_mfma_f32_16x16x32_f16(a[kc], bf, acc[j], 0, 0, 0);
        }
    }

    // ---- epilogue: rowsum[r] = sum_n v[n]*tanh(acc + addv[n]) ----
    const float* avb = addv + b * DH;
    float rowsum[4] = {0.f, 0.f, 0.f, 0.f};
#pragma unroll
    for (int j = 0; j < 32; ++j) {
        int n = j * 16 + l15;
        float av = avb[n];
        float vv = v[n];
#pragma unroll
        for (int r = 0; r < 4; ++r)
            rowsum[r] += vv * fast_tanh(acc[j][r] + av);
    }
#pragma unroll
    for (int r = 0; r < 4; ++r) {
        float s = rowsum[r];
        s += __shfl_xor(s, 1, 16);
        s += __shfl_xor(s, 2, 16);
        s += __shfl_xor(s, 4, 16);
        s += __shfl_xor(s, 8, 16);
        rowsum[r] = s;
    }
    if (l15 == 0) {
        int isByte = maskflag[0];
#pragma unroll
        for (int r = 0; r < 4; ++r) {
            int s = s0 + wave * 16 + q * 4 + r;   // C layout: row = q*4 + r
            int msk = isByte ? (int)((const unsigned char*)mask)[b * S_ + s]
                             : ((const int*)mask)[b * S_ + s];
            scores[b * S_ + s] = msk ? -__builtin_inff() : rowsum[r];
        }
    }
}

// ---------------- softmax ----------------
__global__ void softmax_kernel(const float* __restrict__ scores,
                               float* __restrict__ attn) {
    int b = blockIdx.x, tid = threadIdx.x;
    const float* sr = scores + b * S_;
    float mx = -__builtin_inff();
    for (int s = tid; s < S_; s += 256) mx = fmaxf(mx, sr[s]);
    for (int o = 1; o < 64; o <<= 1) mx = fmaxf(mx, __shfl_xor(mx, o, 64));
    __shared__ float rbuf[4];
    int wv = tid >> 6, ln = tid & 63;
    if (ln == 0) rbuf[wv] = mx;
    __syncthreads();
    mx = fmaxf(fmaxf(rbuf[0], rbuf[1]), fmaxf(rbuf[2], rbuf[3]));
    float sum = 0.f;
    for (int s = tid; s < S_; s += 256) sum += __expf(sr[s] - mx);
    for (int o = 1; o < 64; o <<= 1) sum += __shfl_xor(sum, o, 64);
    __syncthreads();
    if (ln == 0) rbuf[wv] = sum;
    __syncthreads();
    sum = rbuf[0] + rbuf[1] + rbuf[2] + rbuf[3];
    float inv = 1.f / sum;
    float* ab = attn + b * S_;
    for (int s = tid; s < S_; s += 256) ab[s] = __expf(sr[s] - mx) * inv;
}

// ---------------- weighted context sum (sparse skip) ----------------
__global__ __launch_bounds__(256)
void wsum_kernel(const float* __restrict__ context,
                 const float* __restrict__ attn,
                 float* __restrict__ wsum) {
    int b  = blockIdx.x >> 5;
    int s0 = (blockIdx.x & 31) * 128;
    int tid = threadIdx.x;
    float acc0 = 0.f, acc1 = 0.f;
    const float* cb = context + ((size_t)b * S_ + s0) * DIN;
    const float* ab = attn + b * S_ + s0;
    for (int s = 0; s < 128; ++s) {
        float w = ab[s];            // uniform across block -> uniform branch
        if (w > 1e-8f) {
            acc0 += w * cb[(size_t)s * DIN + tid];
            acc1 += w * cb[(size_t)s * DIN + tid + 256];
        }
    }
    atomicAdd(&wsum[b * DIN + tid], acc0);
    atomicAdd(&wsum[b * DIN + tid + 256], acc1);
}

// ---------------- hidden = W_ctx @ wsum + b_ctx ----------------
__global__ void hidden_kernel(const float* __restrict__ W_ctx,
                              const float* __restrict__ b_ctx,
                              const float* __restrict__ wsum,
                              float* __restrict__ hidden) {
    int b = blockIdx.x >> 1;
    int tid = threadIdx.x;
    int h = ((blockIdx.x & 1) << 8) + tid;
    __shared__ float wrow[DIN];
    wrow[tid]       = wsum[b * DIN + tid];
    wrow[tid + 256] = wsum[b * DIN + tid + 256];
    __syncthreads();
    const float* wr = W_ctx + (size_t)h * DIN;
    float acc = 0.f;
    for (int k = 0; k < DIN; k += 4) {
        float4 w4 = *(const float4*)(wr + k);
        acc += w4.x * wrow[k] + w4.y * wrow[k + 1]
             + w4.z * wrow[k + 2] + w4.w * wrow[k + 3];
    }
    hidden[b * DH + h] = acc + b_ctx[h];
}

extern "C" void kernel_launch(void* const* d_in, const int* in_sizes, int n_in,
                              void* d_out, int out_size, void* d_ws, size_t ws_size,
                              hipStream_t stream) {
    const float* input   = (const float*)d_in[0];
    const float* context = (const float*)d_in[1];
    const void*  mask    = d_in[2];
    const float* W_in    = (const float*)d_in[3];
    const float* b_in    = (const float*)d_in[4];
    const float* W_ctx   = (const float*)d_in[5];
    const float* b_ctx   = (const float*)d_in[6];
    const float* v       = (const float*)d_in[7];

    char* ws = (char*)d_ws;
    _Float16* W16   = (_Float16*)ws;
    float* addv     = (float*)(ws + 524288);
    float* scores   = (float*)(ws + 557056);
    float* wsum     = (float*)(ws + 819200);
    int*   maskflag = (int*)(ws + 851968);

    float* hidden = (float*)d_out;                  // [16,512]
    float* attn   = (float*)d_out + B_ * DH;        // [16,4096]

    prep_kernel<<<290, 256, 0, stream>>>(input, W_in, b_in, W_ctx, b_ctx, mask,
                                         W16, addv, wsum, maskflag);
    score_kernel<<<B_ * (S_ / MT), 256, 0, stream>>>(context, W16, addv, v,
                                                     mask, maskflag, scores);
    softmax_kernel<<<B_, 256, 0, stream>>>(scores, attn);
    wsum_kernel<<<B_ * 32, 256, 0, stream>>>(context, attn, wsum);
    hidden_kernel<<<B_ * 2, 256, 0, stream>>>(W_ctx, b_ctx, wsum, hidden);
}

// Round 3
// 416.634 us; speedup vs baseline: 1.0919x; 1.0345x over previous
//
#include <hip/hip_runtime.h>
#include <hip/hip_bf16.h>

#define B_  16
#define S_  4096
#define DIN 512
#define DH  512

typedef _Float16 f16x8 __attribute__((ext_vector_type(8)));
typedef float    f32x4 __attribute__((ext_vector_type(4)));

// ---------------- ws layout (bytes) ----------------
// W16     : [DH][DIN] fp16      @ 0        (524288)
// addv    : [B_][DH]  f32       @ 524288   (32768)   = input@W_in.T + b_in + b_ctx
// scores  : [B_][S_]  f32       @ 557056   (262144)
// maskflag: int                 @ 851968   (4)       1 = mask is byte-per-elem

__device__ __forceinline__ float fast_tanh(float x) {
    float e = __expf(2.f * x);
    return 1.f - 2.f * __builtin_amdgcn_rcpf(e + 1.f);
}

__device__ __forceinline__ void gload_lds16(const void* g, void* l) {
    __builtin_amdgcn_global_load_lds(
        (const __attribute__((address_space(1))) void*)g,
        (__attribute__((address_space(3))) void*)l, 16, 0, 0);
}

// ---------------- prep ----------------
__global__ void prep_kernel(const float* __restrict__ input,
                            const float* __restrict__ W_in,
                            const float* __restrict__ b_in,
                            const float* __restrict__ W_ctx,
                            const float* __restrict__ b_ctx,
                            const void*  __restrict__ mask,
                            _Float16* __restrict__ W16,
                            float* __restrict__ addv,
                            int* __restrict__ maskflag) {
    int blk = blockIdx.x;
    int tid = threadIdx.x;
    if (blk < 256) {
        // W_ctx fp32 -> fp16 : 262144 elems, 4/thread
        int base = blk * 1024 + tid * 4;
        float4 wv = *(const float4*)(W_ctx + base);
        union { _Float16 f[4]; ushort4 u; } cv;
        cv.f[0] = (_Float16)wv.x; cv.f[1] = (_Float16)wv.y;
        cv.f[2] = (_Float16)wv.z; cv.f[3] = (_Float16)wv.w;
        *(ushort4*)(W16 + base) = cv.u;
    } else if (blk < 288) {
        int t = blk - 256;
        int b = t >> 1;
        int h = ((t & 1) << 8) + tid;
        __shared__ float inrow[DIN];
        inrow[tid]       = input[b * DIN + tid];
        inrow[tid + 256] = input[b * DIN + tid + 256];
        __syncthreads();
        const float* wr = W_in + (size_t)h * DIN;
        float acc = 0.f;
        for (int k = 0; k < DIN; k += 4) {
            float4 w4 = *(const float4*)(wr + k);
            acc += w4.x * inrow[k] + w4.y * inrow[k + 1]
                 + w4.z * inrow[k + 2] + w4.w * inrow[k + 3];
        }
        addv[b * DH + h] = acc + b_in[h] + b_ctx[h];
    } else {
        // detect mask dtype: int32 bool has nonzero bytes only at i%4==0
        const unsigned char* mb = (const unsigned char*)mask;
        int found = 0;
        for (int i = tid; i < B_ * S_; i += 256)
            if ((i & 3) != 0 && mb[i] != 0) found = 1;
        __shared__ int f;
        if (tid == 0) f = 0;
        __syncthreads();
        if (found) atomicOr(&f, 1);
        __syncthreads();
        if (tid == 0) maskflag[0] = f;
    }
}

// ---------------- score: v . tanh(addv + context@W16^T), masked ----------------
// Block: 256 thr (4 waves), 32 s-rows/wave (2 m-tiles, A in regs, full K).
// N processed in 8 windows of 64 (4 n-tiles); acc only spans the window
// (tanh sum over n is outside tanh -> partial-n accumulation is exact).
// B staged per (window, k-chunk=32 halves) into double-buffered 8KB LDS via
// global_load_lds w16; one barrier/chunk, stage issued after barrier so the
// drain at the NEXT barrier has a full compute phase of slack.
// Grid: 16 b x 32 s-tiles = 512 blocks = 2/CU.

__global__ __launch_bounds__(256, 2)
void score_kernel(const float* __restrict__ context,
                  const _Float16* __restrict__ W16,
                  const float* __restrict__ addv,
                  const float* __restrict__ v,
                  const void* __restrict__ mask,
                  const int* __restrict__ maskflag,
                  float* __restrict__ scores) {
    __shared__ _Float16 Bs[2][4 * 512];   // dbuf, 4KB each

    const int tid  = threadIdx.x;
    const int wave = tid >> 6;
    const int lane = tid & 63;
    const int l15  = lane & 15;
    const int q    = lane >> 4;
    const int b    = blockIdx.x >> 5;
    const int s0   = (blockIdx.x & 31) * 128;

    // ---- A fragments (registers, full K): rows s0+wave*32+t*16+l15 ----
    f16x8 a[2][16];
#pragma unroll
    for (int t = 0; t < 2; ++t) {
        const float* arow = context +
            ((size_t)b * S_ + s0 + wave * 32 + t * 16 + l15) * DIN + q * 8;
#pragma unroll
        for (int kc = 0; kc < 16; ++kc) {
            float4 x0 = *(const float4*)(arow + kc * 32);
            float4 x1 = *(const float4*)(arow + kc * 32 + 4);
            f16x8 tt;
            tt[0] = (_Float16)x0.x; tt[1] = (_Float16)x0.y;
            tt[2] = (_Float16)x0.z; tt[3] = (_Float16)x0.w;
            tt[4] = (_Float16)x1.x; tt[5] = (_Float16)x1.y;
            tt[6] = (_Float16)x1.z; tt[7] = (_Float16)x1.w;
            a[t][kc] = tt;
        }
    }

    const float* avb = addv + b * DH;
    float rowsum[2][4] = {{0.f,0.f,0.f,0.f},{0.f,0.f,0.f,0.f}};

    // stage step 0 (win 0, kc 0): wave w loads n-tile j=w (1KB)
    {
        const _Float16* g = W16 + (size_t)(wave * 16 + l15) * DIN + q * 8;
        gload_lds16(g, &Bs[0][wave * 512]);
    }

    int step = 0;
    for (int win = 0; win < 8; ++win) {
        f32x4 acc[2][4];
#pragma unroll
        for (int t = 0; t < 2; ++t)
#pragma unroll
            for (int j = 0; j < 4; ++j) acc[t][j] = (f32x4){0.f,0.f,0.f,0.f};

#pragma unroll
        for (int kc = 0; kc < 16; ++kc) {
            __syncthreads();            // drains own stage(step); all waves synced
            int buf = step & 1;
            int ns  = step + 1;
            if (ns < 128) {             // stage next chunk into other buffer
                int win_s = ns >> 4, kc_s = ns & 15;
                const _Float16* g = W16 +
                    (size_t)(win_s * 64 + wave * 16 + l15) * DIN + kc_s * 32 + q * 8;
                gload_lds16(g, &Bs[ns & 1][wave * 512]);
            }
            f16x8 bf0 = *(const f16x8*)&Bs[buf][0 * 512 + q * 128 + l15 * 8];
            f16x8 bf1 = *(const f16x8*)&Bs[buf][1 * 512 + q * 128 + l15 * 8];
            f16x8 bf2 = *(const f16x8*)&Bs[buf][2 * 512 + q * 128 + l15 * 8];
            f16x8 bf3 = *(const f16x8*)&Bs[buf][3 * 512 + q * 128 + l15 * 8];
            acc[0][0] = __builtin_amdgcn_mfma_f32_16x16x32_f16(a[0][kc], bf0, acc[0][0], 0, 0, 0);
            acc[1][0] = __builtin_amdgcn_mfma_f32_16x16x32_f16(a[1][kc], bf0, acc[1][0], 0, 0, 0);
            acc[0][1] = __builtin_amdgcn_mfma_f32_16x16x32_f16(a[0][kc], bf1, acc[0][1], 0, 0, 0);
            acc[1][1] = __builtin_amdgcn_mfma_f32_16x16x32_f16(a[1][kc], bf1, acc[1][1], 0, 0, 0);
            acc[0][2] = __builtin_amdgcn_mfma_f32_16x16x32_f16(a[0][kc], bf2, acc[0][2], 0, 0, 0);
            acc[1][2] = __builtin_amdgcn_mfma_f32_16x16x32_f16(a[1][kc], bf2, acc[1][2], 0, 0, 0);
            acc[0][3] = __builtin_amdgcn_mfma_f32_16x16x32_f16(a[0][kc], bf3, acc[0][3], 0, 0, 0);
            acc[1][3] = __builtin_amdgcn_mfma_f32_16x16x32_f16(a[1][kc], bf3, acc[1][3], 0, 0, 0);
            ++step;
        }
        // window epilogue (overlaps the already-issued next-window stage)
#pragma unroll
        for (int j = 0; j < 4; ++j) {
            int n = win * 64 + j * 16 + l15;
            float av = avb[n];
            float vv = v[n];
#pragma unroll
            for (int t = 0; t < 2; ++t)
#pragma unroll
                for (int r = 0; r < 4; ++r)
                    rowsum[t][r] += vv * fast_tanh(acc[t][j][r] + av);
        }
    }

    // ---- reduce over l15, write scores with mask ----
    int isByte = maskflag[0];
#pragma unroll
    for (int t = 0; t < 2; ++t)
#pragma unroll
        for (int r = 0; r < 4; ++r) {
            float s = rowsum[t][r];
            s += __shfl_xor(s, 1, 16);
            s += __shfl_xor(s, 2, 16);
            s += __shfl_xor(s, 4, 16);
            s += __shfl_xor(s, 8, 16);
            if (l15 == 0) {
                int srow = s0 + wave * 32 + t * 16 + q * 4 + r;  // C row = q*4+r
                int idx = b * S_ + srow;
                int msk = isByte ? (int)((const unsigned char*)mask)[idx]
                                 : ((const int*)mask)[idx];
                scores[idx] = msk ? -__builtin_inff() : s;
            }
        }
}

// ---------------- fused softmax + select + weighted-sum + project ----------------
// One block per batch row. Softmax is extremely peaked (score std ~13), so
// attn>1e-9 selects ~tens of rows; dropped mass <= 4096e-9 -> err ~1e-5.
__global__ __launch_bounds__(256)
void final_kernel(const float* __restrict__ scores,
                  const float* __restrict__ context,
                  const float* __restrict__ W_ctx,
                  const float* __restrict__ b_ctx,
                  float* __restrict__ attn,
                  float* __restrict__ hidden) {
    __shared__ float rbuf[4];
    __shared__ float wsumS[DIN];
    __shared__ int   selIdx[S_];
    __shared__ float selW[S_];
    __shared__ int   selCount;

    int b = blockIdx.x, tid = threadIdx.x;
    int wv = tid >> 6, ln = tid & 63;
    const float* sr = scores + b * S_;

    float mx = -__builtin_inff();
    for (int s = tid; s < S_; s += 256) mx = fmaxf(mx, sr[s]);
    for (int o = 1; o < 64; o <<= 1) mx = fmaxf(mx, __shfl_xor(mx, o, 64));
    if (ln == 0) rbuf[wv] = mx;
    __syncthreads();
    mx = fmaxf(fmaxf(rbuf[0], rbuf[1]), fmaxf(rbuf[2], rbuf[3]));
    __syncthreads();

    float sum = 0.f;
    for (int s = tid; s < S_; s += 256) sum += __expf(sr[s] - mx);
    for (int o = 1; o < 64; o <<= 1) sum += __shfl_xor(sum, o, 64);
    if (ln == 0) rbuf[wv] = sum;
    if (tid == 0) selCount = 0;
    __syncthreads();
    sum = rbuf[0] + rbuf[1] + rbuf[2] + rbuf[3];
    float inv = 1.f / sum;

    float* ab = attn + b * S_;
    for (int s = tid; s < S_; s += 256) {
        float p = __expf(sr[s] - mx) * inv;
        ab[s] = p;
        if (p > 1e-9f) {
            int k = atomicAdd(&selCount, 1);
            selIdx[k] = s;
            selW[k]  = p;
        }
    }
    __syncthreads();

    int cnt = selCount;
    float acc0 = 0.f, acc1 = 0.f;
    for (int i = 0; i < cnt; ++i) {
        int s = selIdx[i];
        float w = selW[i];
        const float* cr = context + ((size_t)b * S_ + s) * DIN;
        acc0 += w * cr[tid];
        acc1 += w * cr[tid + 256];
    }
    wsumS[tid]       = acc0;
    wsumS[tid + 256] = acc1;
    __syncthreads();

    // hidden[b][h] = W_ctx[h,:] . wsum + b_ctx[h]  (2 h per thread)
#pragma unroll
    for (int hh = 0; hh < 2; ++hh) {
        int h = tid + hh * 256;
        const float* wr = W_ctx + (size_t)h * DIN;
        float acc = 0.f;
        for (int k = 0; k < DIN; k += 4) {
            float4 w4 = *(const float4*)(wr + k);
            acc += w4.x * wsumS[k] + w4.y * wsumS[k + 1]
                 + w4.z * wsumS[k + 2] + w4.w * wsumS[k + 3];
        }
        hidden[b * DH + h] = acc + b_ctx[h];
    }
}

extern "C" void kernel_launch(void* const* d_in, const int* in_sizes, int n_in,
                              void* d_out, int out_size, void* d_ws, size_t ws_size,
                              hipStream_t stream) {
    const float* input   = (const float*)d_in[0];
    const float* context = (const float*)d_in[1];
    const void*  mask    = d_in[2];
    const float* W_in    = (const float*)d_in[3];
    const float* b_in    = (const float*)d_in[4];
    const float* W_ctx   = (const float*)d_in[5];
    const float* b_ctx   = (const float*)d_in[6];
    const float* v       = (const float*)d_in[7];

    char* ws = (char*)d_ws;
    _Float16* W16   = (_Float16*)ws;
    float* addv     = (float*)(ws + 524288);
    float* scores   = (float*)(ws + 557056);
    int*   maskflag = (int*)(ws + 851968);

    float* hidden = (float*)d_out;                  // [16,512]
    float* attn   = (float*)d_out + B_ * DH;        // [16,4096]

    prep_kernel<<<289, 256, 0, stream>>>(input, W_in, b_in, W_ctx, b_ctx, mask,
                                         W16, addv, maskflag);
    score_kernel<<<512, 256, 0, stream>>>(context, W16, addv, v,
                                          mask, maskflag, scores);
    final_kernel<<<B_, 256, 0, stream>>>(scores, context, W_ctx, b_ctx,
                                         attn, hidden);
}

// Round 4
// 317.079 us; speedup vs baseline: 1.4347x; 1.3140x over previous
//
#include <hip/hip_runtime.h>
#include <hip/hip_bf16.h>

#define B_  16
#define S_  4096
#define DIN 512
#define DH  512

typedef _Float16 f16x8 __attribute__((ext_vector_type(8)));
typedef float    f32x4 __attribute__((ext_vector_type(4)));

// ---------------- ws layout (bytes) ----------------
// W16     : [DH][DIN] fp16      @ 0        (524288)
// addv    : [B_][DH]  f32       @ 524288   (32768)   = input@W_in.T + b_in + b_ctx
// scores  : [B_][S_]  f32       @ 557056   (262144)
// maskflag: int                 @ 851968   (4)       1 = mask is byte-per-elem

__device__ __forceinline__ float fast_tanh(float x) {
    float e = __expf(2.f * x);
    return 1.f - 2.f * __builtin_amdgcn_rcpf(e + 1.f);
}

__device__ __forceinline__ void gload_lds16(const void* g, void* l) {
    __builtin_amdgcn_global_load_lds(
        (const __attribute__((address_space(1))) void*)g,
        (__attribute__((address_space(3))) void*)l, 16, 0, 0);
}

// ---------------- prep ----------------
__global__ void prep_kernel(const float* __restrict__ input,
                            const float* __restrict__ W_in,
                            const float* __restrict__ b_in,
                            const float* __restrict__ W_ctx,
                            const float* __restrict__ b_ctx,
                            const void*  __restrict__ mask,
                            _Float16* __restrict__ W16,
                            float* __restrict__ addv,
                            int* __restrict__ maskflag) {
    int blk = blockIdx.x;
    int tid = threadIdx.x;
    if (blk < 256) {
        // W_ctx fp32 -> fp16 : 262144 elems, 4/thread
        int base = blk * 1024 + tid * 4;
        float4 wv = *(const float4*)(W_ctx + base);
        union { _Float16 f[4]; ushort4 u; } cv;
        cv.f[0] = (_Float16)wv.x; cv.f[1] = (_Float16)wv.y;
        cv.f[2] = (_Float16)wv.z; cv.f[3] = (_Float16)wv.w;
        *(ushort4*)(W16 + base) = cv.u;
    } else if (blk < 288) {
        int t = blk - 256;
        int b = t >> 1;
        int h = ((t & 1) << 8) + tid;
        __shared__ float inrow[DIN];
        inrow[tid]       = input[b * DIN + tid];
        inrow[tid + 256] = input[b * DIN + tid + 256];
        __syncthreads();
        const float* wr = W_in + (size_t)h * DIN;
        float acc = 0.f;
        for (int k = 0; k < DIN; k += 4) {
            float4 w4 = *(const float4*)(wr + k);
            acc += w4.x * inrow[k] + w4.y * inrow[k + 1]
                 + w4.z * inrow[k + 2] + w4.w * inrow[k + 3];
        }
        addv[b * DH + h] = acc + b_in[h] + b_ctx[h];
    } else {
        // mask dtype detect, VECTORIZED: byte-mask packs bools in all 4 byte
        // lanes of a word; int32 bools are 0/1 (upper 3 bytes always 0).
        // Scan first 65536 bytes = 4096 uint4 -> 16 loads/thread.
        const uint4* m4 = (const uint4*)mask;
        unsigned int orw = 0;
#pragma unroll
        for (int it = 0; it < 16; ++it) {
            uint4 w = m4[it * 256 + tid];
            orw |= (w.x | w.y | w.z | w.w);
        }
        int found = ((orw & 0xFFFFFF00u) != 0) ? 1 : 0;
        __shared__ int f;
        if (tid == 0) f = 0;
        __syncthreads();
        if (found) atomicOr(&f, 1);
        __syncthreads();
        if (tid == 0) maskflag[0] = f;
    }
}

// ---------------- score: v . tanh(addv + context@W16^T), masked ----------------
// Block: 256 thr (4 waves), 32 s-rows/wave (2 m-tiles, A in regs, full K).
// N in 8 windows of 64 (partial-n accumulation is exact: tanh sum is over n).
// B staged in CHUNKS of 32KB (64 n-rows x 256 k) into a 2x32KB double buffer
// via global_load_lds w16 — 16 barriers total, each drain has ~8 kc of
// compute slack to hide L2/HBM latency. Grid: 16 b x 32 s-tiles = 512 = 2/CU.

__global__ __launch_bounds__(256, 2)
void score_kernel(const float* __restrict__ context,
                  const _Float16* __restrict__ W16,
                  const float* __restrict__ addv,
                  const float* __restrict__ v,
                  const void* __restrict__ mask,
                  const int* __restrict__ maskflag,
                  float* __restrict__ scores) {
    __shared__ _Float16 Bs[2][16384];   // 32KB each

    const int tid  = threadIdx.x;
    const int wave = tid >> 6;
    const int lane = tid & 63;
    const int l15  = lane & 15;
    const int q    = lane >> 4;
    const int b    = blockIdx.x >> 5;
    const int s0   = (blockIdx.x & 31) * 128;

    // ---- A fragments (registers, full K): rows s0+wave*32+t*16+l15 ----
    f16x8 a[2][16];
#pragma unroll
    for (int t = 0; t < 2; ++t) {
        const float* arow = context +
            ((size_t)b * S_ + s0 + wave * 32 + t * 16 + l15) * DIN + q * 8;
#pragma unroll
        for (int kc = 0; kc < 16; ++kc) {
            float4 x0 = *(const float4*)(arow + kc * 32);
            float4 x1 = *(const float4*)(arow + kc * 32 + 4);
            f16x8 tt;
            tt[0] = (_Float16)x0.x; tt[1] = (_Float16)x0.y;
            tt[2] = (_Float16)x0.z; tt[3] = (_Float16)x0.w;
            tt[4] = (_Float16)x1.x; tt[5] = (_Float16)x1.y;
            tt[6] = (_Float16)x1.z; tt[7] = (_Float16)x1.w;
            a[t][kc] = tt;
        }
    }

    const float* avb = addv + b * DH;
    float rowsum[2][4] = {{0.f,0.f,0.f,0.f},{0.f,0.f,0.f,0.f}};

    // chunk c (0..15): win = c>>1, khalf = c&1 (k in [khalf*256, +256)).
    // 32 stage instrs/chunk (kl 0..7 x j 0..3), wave does 8; instr id = kl*4+j
    // -> LDS halves [id*512, +512), lane L at +L*16B (q*256B + l15*16B).
    // Read layout: Bs[buf][(kl*4+j)*512 + q*128 + l15*8] — 2 lanes/bank, free.
#define STAGE_CHUNK(c_)                                                        \
    {                                                                          \
        int win_s = (c_) >> 1, kh_s = (c_) & 1;                                \
        _Float16* dst = &Bs[(c_) & 1][0];                                      \
        _Pragma("unroll")                                                      \
        for (int u = 0; u < 8; ++u) {                                          \
            int id = wave * 8 + u;                                             \
            int kl = id >> 2, j = id & 3;                                      \
            const _Float16* g = W16 +                                          \
                (size_t)(win_s * 64 + j * 16 + l15) * DIN +                    \
                kh_s * 256 + kl * 32 + q * 8;                                  \
            gload_lds16(g, dst + id * 512);                                    \
        }                                                                      \
    }

    STAGE_CHUNK(0);

    for (int win = 0; win < 8; ++win) {
        f32x4 acc[2][4];
#pragma unroll
        for (int t = 0; t < 2; ++t)
#pragma unroll
            for (int j = 0; j < 4; ++j) acc[t][j] = (f32x4){0.f,0.f,0.f,0.f};

#pragma unroll
        for (int kh = 0; kh < 2; ++kh) {
            int c = win * 2 + kh;
            __syncthreads();            // drains stage(c); prior reads of buf^1 done
            if (c + 1 < 16) STAGE_CHUNK(c + 1);
            const _Float16* Bbuf = &Bs[c & 1][0];
#pragma unroll
            for (int kl = 0; kl < 8; ++kl) {
                int kc = kh * 8 + kl;
                f16x8 bf0 = *(const f16x8*)&Bbuf[(kl * 4 + 0) * 512 + q * 128 + l15 * 8];
                f16x8 bf1 = *(const f16x8*)&Bbuf[(kl * 4 + 1) * 512 + q * 128 + l15 * 8];
                f16x8 bf2 = *(const f16x8*)&Bbuf[(kl * 4 + 2) * 512 + q * 128 + l15 * 8];
                f16x8 bf3 = *(const f16x8*)&Bbuf[(kl * 4 + 3) * 512 + q * 128 + l15 * 8];
                acc[0][0] = __builtin_amdgcn_mfma_f32_16x16x32_f16(a[0][kc], bf0, acc[0][0], 0, 0, 0);
                acc[1][0] = __builtin_amdgcn_mfma_f32_16x16x32_f16(a[1][kc], bf0, acc[1][0], 0, 0, 0);
                acc[0][1] = __builtin_amdgcn_mfma_f32_16x16x32_f16(a[0][kc], bf1, acc[0][1], 0, 0, 0);
                acc[1][1] = __builtin_amdgcn_mfma_f32_16x16x32_f16(a[1][kc], bf1, acc[1][1], 0, 0, 0);
                acc[0][2] = __builtin_amdgcn_mfma_f32_16x16x32_f16(a[0][kc], bf2, acc[0][2], 0, 0, 0);
                acc[1][2] = __builtin_amdgcn_mfma_f32_16x16x32_f16(a[1][kc], bf2, acc[1][2], 0, 0, 0);
                acc[0][3] = __builtin_amdgcn_mfma_f32_16x16x32_f16(a[0][kc], bf3, acc[0][3], 0, 0, 0);
                acc[1][3] = __builtin_amdgcn_mfma_f32_16x16x32_f16(a[1][kc], bf3, acc[1][3], 0, 0, 0);
            }
        }
        // window epilogue (overlaps the in-flight next-chunk stage)
#pragma unroll
        for (int j = 0; j < 4; ++j) {
            int n = win * 64 + j * 16 + l15;
            float av = avb[n];
            float vv = v[n];
#pragma unroll
            for (int t = 0; t < 2; ++t)
#pragma unroll
                for (int r = 0; r < 4; ++r)
                    rowsum[t][r] += vv * fast_tanh(acc[t][j][r] + av);
        }
    }

    // ---- reduce over l15, write scores with mask ----
    int isByte = maskflag[0];
#pragma unroll
    for (int t = 0; t < 2; ++t)
#pragma unroll
        for (int r = 0; r < 4; ++r) {
            float s = rowsum[t][r];
            s += __shfl_xor(s, 1, 16);
            s += __shfl_xor(s, 2, 16);
            s += __shfl_xor(s, 4, 16);
            s += __shfl_xor(s, 8, 16);
            if (l15 == 0) {
                int srow = s0 + wave * 32 + t * 16 + q * 4 + r;  // C row = q*4+r
                int idx = b * S_ + srow;
                int msk = isByte ? (int)((const unsigned char*)mask)[idx]
                                 : ((const int*)mask)[idx];
                scores[idx] = msk ? -__builtin_inff() : s;
            }
        }
}

// ---------------- fused softmax + select + weighted-sum + project ----------------
// One block per batch row. Softmax is extremely peaked (score std ~14), so
// attn>1e-9 selects ~50-150 rows; dropped mass <= 4096e-9 -> err ~1e-5.
__global__ __launch_bounds__(256)
void final_kernel(const float* __restrict__ scores,
                  const float* __restrict__ context,
                  const float* __restrict__ W_ctx,
                  const float* __restrict__ b_ctx,
                  float* __restrict__ attn,
                  float* __restrict__ hidden) {
    __shared__ float rbuf[4];
    __shared__ float wsumS[DIN];
    __shared__ int   selIdx[S_];
    __shared__ float selW[S_];
    __shared__ int   selCount;

    int b = blockIdx.x, tid = threadIdx.x;
    int wv = tid >> 6, ln = tid & 63;
    const float* sr = scores + b * S_;

    float mx = -__builtin_inff();
    for (int s = tid; s < S_; s += 256) mx = fmaxf(mx, sr[s]);
    for (int o = 1; o < 64; o <<= 1) mx = fmaxf(mx, __shfl_xor(mx, o, 64));
    if (ln == 0) rbuf[wv] = mx;
    __syncthreads();
    mx = fmaxf(fmaxf(rbuf[0], rbuf[1]), fmaxf(rbuf[2], rbuf[3]));
    __syncthreads();

    float sum = 0.f;
    for (int s = tid; s < S_; s += 256) sum += __expf(sr[s] - mx);
    for (int o = 1; o < 64; o <<= 1) sum += __shfl_xor(sum, o, 64);
    if (ln == 0) rbuf[wv] = sum;
    if (tid == 0) selCount = 0;
    __syncthreads();
    sum = rbuf[0] + rbuf[1] + rbuf[2] + rbuf[3];
    float inv = 1.f / sum;

    float* ab = attn + b * S_;
    for (int s = tid; s < S_; s += 256) {
        float p = __expf(sr[s] - mx) * inv;
        ab[s] = p;
        if (p > 1e-9f) {
            int k = atomicAdd(&selCount, 1);
            selIdx[k] = s;
            selW[k]  = p;
        }
    }
    __syncthreads();

    int cnt = selCount;
    float acc0 = 0.f, acc1 = 0.f;
    for (int i = 0; i < cnt; ++i) {
        int s = selIdx[i];
        float w = selW[i];
        const float* cr = context + ((size_t)b * S_ + s) * DIN;
        acc0 += w * cr[tid];
        acc1 += w * cr[tid + 256];
    }
    wsumS[tid]       = acc0;
    wsumS[tid + 256] = acc1;
    __syncthreads();

    // hidden[b][h] = W_ctx[h,:] . wsum + b_ctx[h]  (2 h per thread)
#pragma unroll
    for (int hh = 0; hh < 2; ++hh) {
        int h = tid + hh * 256;
        const float* wr = W_ctx + (size_t)h * DIN;
        float acc = 0.f;
        for (int k = 0; k < DIN; k += 4) {
            float4 w4 = *(const float4*)(wr + k);
            acc += w4.x * wsumS[k] + w4.y * wsumS[k + 1]
                 + w4.z * wsumS[k + 2] + w4.w * wsumS[k + 3];
        }
        hidden[b * DH + h] = acc + b_ctx[h];
    }
}

extern "C" void kernel_launch(void* const* d_in, const int* in_sizes, int n_in,
                              void* d_out, int out_size, void* d_ws, size_t ws_size,
                              hipStream_t stream) {
    const float* input   = (const float*)d_in[0];
    const float* context = (const float*)d_in[1];
    const void*  mask    = d_in[2];
    const float* W_in    = (const float*)d_in[3];
    const float* b_in    = (const float*)d_in[4];
    const float* W_ctx   = (const float*)d_in[5];
    const float* b_ctx   = (const float*)d_in[6];
    const float* v       = (const float*)d_in[7];

    char* ws = (char*)d_ws;
    _Float16* W16   = (_Float16*)ws;
    float* addv     = (float*)(ws + 524288);
    float* scores   = (float*)(ws + 557056);
    int*   maskflag = (int*)(ws + 851968);

    float* hidden = (float*)d_out;                  // [16,512]
    float* attn   = (float*)d_out + B_ * DH;        // [16,4096]

    prep_kernel<<<289, 256, 0, stream>>>(input, W_in, b_in, W_ctx, b_ctx, mask,
                                         W16, addv, maskflag);
    score_kernel<<<512, 256, 0, stream>>>(context, W16, addv, v,
                                          mask, maskflag, scores);
    final_kernel<<<B_, 256, 0, stream>>>(scores, context, W_ctx, b_ctx,
                                         attn, hidden);
}